// Round 12
// baseline (372.115 us; speedup 1.0000x reference)
//
#include <hip/hip_runtime.h>

typedef __bf16 bf16x8 __attribute__((ext_vector_type(8)));
typedef __bf16 bf16x4 __attribute__((ext_vector_type(4)));
typedef float floatx4 __attribute__((ext_vector_type(4)));

#define AS1(p) ((const __attribute__((address_space(1))) unsigned int*)(p))
#define AS3(p) ((__attribute__((address_space(3))) unsigned int*)(p))

__device__ __forceinline__ void async_cp16(const void* g, void* l) {
  __builtin_amdgcn_global_load_lds(AS1(g), AS3(l), 16, 0, 0);
}

// ---------------------------------------------------------------------------
// BK=64 XOR-swizzled LDS tile [128 rows][64 k] bf16 (chunk = 16B of 8 k,
// 8 chunks/row):  LDS slot s holds G[row = s>>3][chunk (s&7) ^ ((s>>3)&7)].
// Staging linear; source col permuted WITHIN the row's 128B run -> fully
// coalesced. Reads conflict-free (r8/r9 HW-verified family).
// ---------------------------------------------------------------------------

// ---------------------------------------------------------------------------
// Generic bf16 GEMM (round-9 verified form, unchanged):
// C[row][col] = scale * (sum_k A[row,k]*B[col,k] + bias). K % 64 == 0.
// ---------------------------------------------------------------------------
template <bool OUT_F32>
__global__ __launch_bounds__(256, 2) void gemm_bt(
    const __bf16* __restrict__ A, const __bf16* __restrict__ B,
    void* __restrict__ Cv, const float* __restrict__ bias,
    const float* __restrict__ residual, const float* __restrict__ colscale,
    int lda, int ldb, int ldc, long sA, long sB, long sC, long sR, int K,
    int bias_mode, float scale, int swz) {
  __shared__ alignas(16) __bf16 As[128 * 64];
  __shared__ alignas(16) __bf16 Bs[128 * 64];

  const int t = threadIdx.x;
  const int bz = blockIdx.z;
  int bx = blockIdx.x, by = blockIdx.y;
  if (swz) {
    const int xcd = bx & 7, idx = bx >> 3;
    by = xcd + (idx >> 2) * 8;  // row strip 0..31
    bx = idx & 3;               // col block 0..3
  }
  const int m0 = by * 128;
  const int n0 = bx * 128;

  const __bf16* Ab = A + (size_t)bz * sA;
  const __bf16* Bb = B + (size_t)bz * sB;

  const int sr = t >> 3;
  const int sc = ((t & 7) ^ ((t >> 3) & 7)) * 8;
  const __bf16* gA0 = Ab + (size_t)(m0 + sr) * lda + sc;
  const __bf16* gA1 = gA0 + (size_t)32 * lda;
  const __bf16* gA2 = gA0 + (size_t)64 * lda;
  const __bf16* gA3 = gA0 + (size_t)96 * lda;
  const __bf16* gB0 = Bb + (size_t)(n0 + sr) * ldb + sc;
  const __bf16* gB1 = gB0 + (size_t)32 * ldb;
  const __bf16* gB2 = gB0 + (size_t)64 * ldb;
  const __bf16* gB3 = gB0 + (size_t)96 * ldb;
  __bf16* lA0 = &As[t * 8];
  __bf16* lA1 = &As[(t + 256) * 8];
  __bf16* lA2 = &As[(t + 512) * 8];
  __bf16* lA3 = &As[(t + 768) * 8];
  __bf16* lB0 = &Bs[t * 8];
  __bf16* lB1 = &Bs[(t + 256) * 8];
  __bf16* lB2 = &Bs[(t + 512) * 8];
  __bf16* lB3 = &Bs[(t + 768) * 8];

  const int lane = t & 63;
  const int wv = t >> 6;
  const int wm = (wv & 1) * 64;
  const int wn = (wv >> 1) * 64;
  const int l15 = lane & 15;
  const int kg = lane >> 4;
  const int l7 = l15 & 7;

  int aoff0[4], boff0[4], aoff1[4], boff1[4];
#pragma unroll
  for (int i = 0; i < 4; ++i) {
    aoff0[i] = (wm + i * 16 + l15) * 64 + (kg ^ l7) * 8;
    aoff1[i] = (wm + i * 16 + l15) * 64 + ((4 + kg) ^ l7) * 8;
  }
#pragma unroll
  for (int j = 0; j < 4; ++j) {
    boff0[j] = (wn + j * 16 + l15) * 64 + (kg ^ l7) * 8;
    boff1[j] = (wn + j * 16 + l15) * 64 + ((4 + kg) ^ l7) * 8;
  }

  floatx4 acc[4][4] = {};

  const int KT = K >> 6;
  for (int kt = 0; kt < KT; ++kt) {
    const size_t ko = (size_t)kt * 64;
    async_cp16(gA0 + ko, lA0);
    async_cp16(gA1 + ko, lA1);
    async_cp16(gA2 + ko, lA2);
    async_cp16(gA3 + ko, lA3);
    async_cp16(gB0 + ko, lB0);
    async_cp16(gB1 + ko, lB1);
    async_cp16(gB2 + ko, lB2);
    async_cp16(gB3 + ko, lB3);
    __syncthreads();
    bf16x8 af[4], bfr[4];
#pragma unroll
    for (int i = 0; i < 4; ++i) af[i] = *(const bf16x8*)&As[aoff0[i]];
#pragma unroll
    for (int j = 0; j < 4; ++j) bfr[j] = *(const bf16x8*)&Bs[boff0[j]];
#pragma unroll
    for (int i = 0; i < 4; ++i)
#pragma unroll
      for (int j = 0; j < 4; ++j)
        acc[i][j] = __builtin_amdgcn_mfma_f32_16x16x32_bf16(af[i], bfr[j],
                                                            acc[i][j], 0, 0, 0);
#pragma unroll
    for (int i = 0; i < 4; ++i) af[i] = *(const bf16x8*)&As[aoff1[i]];
#pragma unroll
    for (int j = 0; j < 4; ++j) bfr[j] = *(const bf16x8*)&Bs[boff1[j]];
#pragma unroll
    for (int i = 0; i < 4; ++i)
#pragma unroll
      for (int j = 0; j < 4; ++j)
        acc[i][j] = __builtin_amdgcn_mfma_f32_16x16x32_bf16(af[i], bfr[j],
                                                            acc[i][j], 0, 0, 0);
    __syncthreads();
  }

  const int r0 = m0 + wm + (kg << 2);
  const int c0 = n0 + wn + l15;
#pragma unroll
  for (int i = 0; i < 4; ++i) {
#pragma unroll
    for (int r = 0; r < 4; ++r) {
      const int row = r0 + i * 16 + r;
      float brow = 0.f;
      if (bias_mode == 1) brow = bias[row];
#pragma unroll
      for (int j = 0; j < 4; ++j) {
        const int col = c0 + j * 16;
        float v = acc[i][j][r];
        if (OUT_F32 && colscale) v *= colscale[(size_t)bz * 4096 + col];
        if (bias_mode == 1) v += brow;
        v *= scale;
        const size_t off = (size_t)row * ldc + col;
        if (OUT_F32) {
          float* Cf = (float*)Cv + (size_t)bz * sC;
          if (residual) v += residual[(size_t)bz * sR + off];
          Cf[off] = v;
        } else {
          __bf16* Cb = (__bf16*)Cv + (size_t)bz * sC;
          Cb[off] = (__bf16)v;
        }
      }
    }
  }
}

// ---------------------------------------------------------------------------
// G-GEMM with fused ||g_row||^2 partials (round-10 verified, unchanged).
// grid (4 colblk, 32 rowstrip, 4).
// ---------------------------------------------------------------------------
__global__ __launch_bounds__(256, 2) void gemm_g(const __bf16* __restrict__ A,
                                                 const __bf16* __restrict__ B,
                                                 __bf16* __restrict__ C,
                                                 float* __restrict__ gn2p) {
  __shared__ alignas(16) __bf16 As[128 * 64];
  __shared__ alignas(16) __bf16 Bs[128 * 64];

  const int t = threadIdx.x;
  const int bz = blockIdx.z;
  const int m0 = blockIdx.y * 128;  // n rows
  const int n0 = blockIdx.x * 128;  // j cols

  const __bf16* Ab = A + (size_t)bz * 2097152;
  const __bf16* Bb = B;  // shared weights (no batch stride)

  const int sr = t >> 3;
  const int sc = ((t & 7) ^ ((t >> 3) & 7)) * 8;
  const __bf16* gA0 = Ab + (size_t)(m0 + sr) * 512 + sc;
  const __bf16* gA1 = gA0 + (size_t)32 * 512;
  const __bf16* gA2 = gA0 + (size_t)64 * 512;
  const __bf16* gA3 = gA0 + (size_t)96 * 512;
  const __bf16* gB0 = Bb + (size_t)(n0 + sr) * 512 + sc;
  const __bf16* gB1 = gB0 + (size_t)32 * 512;
  const __bf16* gB2 = gB0 + (size_t)64 * 512;
  const __bf16* gB3 = gB0 + (size_t)96 * 512;
  __bf16* lA0 = &As[t * 8];
  __bf16* lA1 = &As[(t + 256) * 8];
  __bf16* lA2 = &As[(t + 512) * 8];
  __bf16* lA3 = &As[(t + 768) * 8];
  __bf16* lB0 = &Bs[t * 8];
  __bf16* lB1 = &Bs[(t + 256) * 8];
  __bf16* lB2 = &Bs[(t + 512) * 8];
  __bf16* lB3 = &Bs[(t + 768) * 8];

  const int lane = t & 63;
  const int wv = t >> 6;
  const int wm = (wv & 1) * 64;
  const int wn = (wv >> 1) * 64;
  const int l15 = lane & 15;
  const int kg = lane >> 4;
  const int l7 = l15 & 7;

  int aoff0[4], boff0[4], aoff1[4], boff1[4];
#pragma unroll
  for (int i = 0; i < 4; ++i) {
    aoff0[i] = (wm + i * 16 + l15) * 64 + (kg ^ l7) * 8;
    aoff1[i] = (wm + i * 16 + l15) * 64 + ((4 + kg) ^ l7) * 8;
  }
#pragma unroll
  for (int j = 0; j < 4; ++j) {
    boff0[j] = (wn + j * 16 + l15) * 64 + (kg ^ l7) * 8;
    boff1[j] = (wn + j * 16 + l15) * 64 + ((4 + kg) ^ l7) * 8;
  }

  floatx4 acc[4][4] = {};

  for (int kt = 0; kt < 8; ++kt) {
    const size_t ko = (size_t)kt * 64;
    async_cp16(gA0 + ko, lA0);
    async_cp16(gA1 + ko, lA1);
    async_cp16(gA2 + ko, lA2);
    async_cp16(gA3 + ko, lA3);
    async_cp16(gB0 + ko, lB0);
    async_cp16(gB1 + ko, lB1);
    async_cp16(gB2 + ko, lB2);
    async_cp16(gB3 + ko, lB3);
    __syncthreads();
    bf16x8 af[4], bfr[4];
#pragma unroll
    for (int i = 0; i < 4; ++i) af[i] = *(const bf16x8*)&As[aoff0[i]];
#pragma unroll
    for (int j = 0; j < 4; ++j) bfr[j] = *(const bf16x8*)&Bs[boff0[j]];
#pragma unroll
    for (int i = 0; i < 4; ++i)
#pragma unroll
      for (int j = 0; j < 4; ++j)
        acc[i][j] = __builtin_amdgcn_mfma_f32_16x16x32_bf16(af[i], bfr[j],
                                                            acc[i][j], 0, 0, 0);
#pragma unroll
    for (int i = 0; i < 4; ++i) af[i] = *(const bf16x8*)&As[aoff1[i]];
#pragma unroll
    for (int j = 0; j < 4; ++j) bfr[j] = *(const bf16x8*)&Bs[boff1[j]];
#pragma unroll
    for (int i = 0; i < 4; ++i)
#pragma unroll
      for (int j = 0; j < 4; ++j)
        acc[i][j] = __builtin_amdgcn_mfma_f32_16x16x32_bf16(af[i], bfr[j],
                                                            acc[i][j], 0, 0, 0);
    __syncthreads();
  }

  __bf16* Cb = C + (size_t)bz * 2097152;
  const int r0 = m0 + wm + (kg << 2);
  const int c0 = n0 + wn + l15;
  const int slot8 = (n0 >> 6) + (wv >> 1);  // colblk*2 + wavehalf, 0..7
#pragma unroll
  for (int i = 0; i < 4; ++i) {
#pragma unroll
    for (int r = 0; r < 4; ++r) {
      const int row = r0 + i * 16 + r;
      float s2 = 0.f;
#pragma unroll
      for (int j = 0; j < 4; ++j) {
        const __bf16 bv = (__bf16)acc[i][j][r];
        Cb[(size_t)row * 512 + c0 + j * 16] = bv;
        const float f = (float)bv;  // round-tripped: matches old gnorm exactly
        s2 += f * f;
      }
#pragma unroll
      for (int off = 1; off < 16; off <<= 1) s2 += __shfl_xor(s2, off);
      if (l15 == 0) gn2p[((size_t)bz * 4096 + row) * 8 + slot8] = s2;
    }
  }
}

// ---------------------------------------------------------------------------
// Two small 512x512x512 GEMMs in one launch. grid (4,4,2).
// (round-8 verified form: BK=32 XOR swizzle; unchanged)
// ---------------------------------------------------------------------------
__global__ __launch_bounds__(256, 2) void gemm_small(
    const __bf16* __restrict__ A0, const __bf16* __restrict__ B0,
    __bf16* __restrict__ C0, const __bf16* __restrict__ A1,
    const __bf16* __restrict__ B1, __bf16* __restrict__ C1, float scale0) {
  __shared__ alignas(16) __bf16 As[128 * 32];
  __shared__ alignas(16) __bf16 Bs[128 * 32];

  const int t = threadIdx.x;
  const int z = blockIdx.z;
  const __bf16* A = z ? A1 : A0;
  const __bf16* B = z ? B1 : B0;
  __bf16* C = z ? C1 : C0;
  const float scale = z ? 1.0f : scale0;
  const int m0 = blockIdx.y * 128;
  const int n0 = blockIdx.x * 128;

  const int sr = t >> 2;
  const int sc = (t & 3) ^ ((t >> 3) & 3);
  const __bf16* gA0 = A + (size_t)(m0 + sr) * 512 + sc * 8;
  const __bf16* gA1 = gA0 + (size_t)64 * 512;
  const __bf16* gB0 = B + (size_t)(n0 + sr) * 512 + sc * 8;
  const __bf16* gB1 = gB0 + (size_t)64 * 512;
  __bf16* lA0 = &As[t * 8];
  __bf16* lA1 = &As[(t + 256) * 8];
  __bf16* lB0 = &Bs[t * 8];
  __bf16* lB1 = &Bs[(t + 256) * 8];

  const int lane = t & 63;
  const int wvv = t >> 6;
  const int wm = (wvv & 1) * 64;
  const int wn = (wvv >> 1) * 64;
  const int l15 = lane & 15;
  const int kg = lane >> 4;

  const int kgs = (kg ^ ((l15 >> 1) & 3)) * 8;
  int aoff[4], boff[4];
#pragma unroll
  for (int i = 0; i < 4; ++i) aoff[i] = (wm + i * 16 + l15) * 32 + kgs;
#pragma unroll
  for (int j = 0; j < 4; ++j) boff[j] = (wn + j * 16 + l15) * 32 + kgs;

  floatx4 acc[4][4] = {};

  for (int kt = 0; kt < 16; ++kt) {
    const size_t ko = (size_t)kt * 32;
    async_cp16(gA0 + ko, lA0);
    async_cp16(gA1 + ko, lA1);
    async_cp16(gB0 + ko, lB0);
    async_cp16(gB1 + ko, lB1);
    __syncthreads();
    bf16x8 af[4], bfr[4];
#pragma unroll
    for (int i = 0; i < 4; ++i) af[i] = *(const bf16x8*)&As[aoff[i]];
#pragma unroll
    for (int j = 0; j < 4; ++j) bfr[j] = *(const bf16x8*)&Bs[boff[j]];
#pragma unroll
    for (int i = 0; i < 4; ++i)
#pragma unroll
      for (int j = 0; j < 4; ++j)
        acc[i][j] = __builtin_amdgcn_mfma_f32_16x16x32_bf16(af[i], bfr[j],
                                                            acc[i][j], 0, 0, 0);
    __syncthreads();
  }

  const int r0 = m0 + wm + (kg << 2);
  const int c0 = n0 + wn + l15;
#pragma unroll
  for (int i = 0; i < 4; ++i)
#pragma unroll
    for (int r = 0; r < 4; ++r) {
      const int row = r0 + i * 16 + r;
#pragma unroll
      for (int j = 0; j < 4; ++j)
        C[(size_t)row * 512 + c0 + j * 16] = (__bf16)(acc[i][j][r] * scale);
    }
}

// ---------------------------------------------------------------------------
// QK^T GEMM + P'' = exp(s - Mhat). 128x128 tile, BK=64 XOR-swizzled
// (round-9/10 verified: ~87 us, 0 conflicts). This round (resubmit of r11):
//  (1) XCD-aware block remap: id=(by*32+bx); xcd=id&7; idx=id>>3;
//      mblk=idx&31, nblk=xcd+(idx>>5)*8 (bijective). Each XCD runs one
//      n-strip's 32 m-blocks consecutively -> G strip stays L2-hot, Ht
//      sweep (4MB) fits its private L2 (T1 mechanism).
//  (2) Lpart layout [mblk][16384]: write = 128 consecutive floats
//      (coalesced; was stride-128B scatter).
// grid (32, 32, 4).
// ---------------------------------------------------------------------------
__global__ __launch_bounds__(256, 2) void gemm_qk(
    const __bf16* __restrict__ G, const __bf16* __restrict__ Ht,
    const float* __restrict__ wvec, const float* __restrict__ sred,
    const float* __restrict__ gn2p, __bf16* __restrict__ SP,
    float* __restrict__ Lpart) {
  __shared__ alignas(16) __bf16 As[128 * 64];
  __shared__ alignas(16) __bf16 Bs[128 * 64];
  __shared__ float smq[128];
  __shared__ float smf[256];

  const int t = threadIdx.x;
  const int bz = blockIdx.z;
  const int id = blockIdx.y * 32 + blockIdx.x;
  const int xcd = id & 7;
  const int idx = id >> 3;
  const int mblk = idx & 31;
  const int m0 = mblk * 128;                    // key cols
  const int n0 = (xcd + (idx >> 5) * 8) * 128;  // query rows
  const long sH = 2097152;

  const __bf16* Ab = G + (size_t)bz * sH;
  const __bf16* Bb = Ht + (size_t)bz * sH;

  const int sr = t >> 3;
  const int sc = ((t & 7) ^ ((t >> 3) & 7)) * 8;
  const __bf16* gA0 = Ab + (size_t)(n0 + sr) * 512 + sc;
  const __bf16* gA1 = gA0 + (size_t)32 * 512;
  const __bf16* gA2 = gA0 + (size_t)64 * 512;
  const __bf16* gA3 = gA0 + (size_t)96 * 512;
  const __bf16* gB0 = Bb + (size_t)(m0 + sr) * 512 + sc;
  const __bf16* gB1 = gB0 + (size_t)32 * 512;
  const __bf16* gB2 = gB0 + (size_t)64 * 512;
  const __bf16* gB3 = gB0 + (size_t)96 * 512;
  __bf16* lA0 = &As[t * 8];
  __bf16* lA1 = &As[(t + 256) * 8];
  __bf16* lA2 = &As[(t + 512) * 8];
  __bf16* lA3 = &As[(t + 768) * 8];
  __bf16* lB0 = &Bs[t * 8];
  __bf16* lB1 = &Bs[(t + 256) * 8];
  __bf16* lB2 = &Bs[(t + 512) * 8];
  __bf16* lB3 = &Bs[(t + 768) * 8];

  const int lane = t & 63;
  const int wv = t >> 6;
  const int wm = (wv & 1) * 64;  // query-row half
  const int wn = (wv >> 1) * 64; // key-col half
  const int l15 = lane & 15;
  const int kg = lane >> 4;
  const int l7 = l15 & 7;

  // Mhat per local query row (hidden under first staging)
  if (t < 128) {
    const floatx4* gp =
        (const floatx4*)&gn2p[((size_t)bz * 4096 + n0 + t) * 8];
    const floatx4 a = gp[0], b = gp[1];
    const float g2 = a[0] + a[1] + a[2] + a[3] + b[0] + b[1] + b[2] + b[3];
    smq[t] = sqrtf(g2) * sqrtf(sred[0]) + sred[1];
  }

  int aoff0[4], boff0[4], aoff1[4], boff1[4];
#pragma unroll
  for (int i = 0; i < 4; ++i) {
    aoff0[i] = (wm + i * 16 + l15) * 64 + (kg ^ l7) * 8;
    aoff1[i] = (wm + i * 16 + l15) * 64 + ((4 + kg) ^ l7) * 8;
  }
#pragma unroll
  for (int j = 0; j < 4; ++j) {
    boff0[j] = (wn + j * 16 + l15) * 64 + (kg ^ l7) * 8;
    boff1[j] = (wn + j * 16 + l15) * 64 + ((4 + kg) ^ l7) * 8;
  }

  floatx4 acc[4][4] = {};

  for (int kt = 0; kt < 8; ++kt) {
    const size_t ko = (size_t)kt * 64;
    async_cp16(gA0 + ko, lA0);
    async_cp16(gA1 + ko, lA1);
    async_cp16(gA2 + ko, lA2);
    async_cp16(gA3 + ko, lA3);
    async_cp16(gB0 + ko, lB0);
    async_cp16(gB1 + ko, lB1);
    async_cp16(gB2 + ko, lB2);
    async_cp16(gB3 + ko, lB3);
    __syncthreads();
    bf16x8 af[4], bfr[4];
#pragma unroll
    for (int i = 0; i < 4; ++i) af[i] = *(const bf16x8*)&As[aoff0[i]];
#pragma unroll
    for (int j = 0; j < 4; ++j) bfr[j] = *(const bf16x8*)&Bs[boff0[j]];
#pragma unroll
    for (int i = 0; i < 4; ++i)
#pragma unroll
      for (int j = 0; j < 4; ++j)
        acc[i][j] = __builtin_amdgcn_mfma_f32_16x16x32_bf16(af[i], bfr[j],
                                                            acc[i][j], 0, 0, 0);
#pragma unroll
    for (int i = 0; i < 4; ++i) af[i] = *(const bf16x8*)&As[aoff1[i]];
#pragma unroll
    for (int j = 0; j < 4; ++j) bfr[j] = *(const bf16x8*)&Bs[boff1[j]];
#pragma unroll
    for (int i = 0; i < 4; ++i)
#pragma unroll
      for (int j = 0; j < 4; ++j)
        acc[i][j] = __builtin_amdgcn_mfma_f32_16x16x32_bf16(af[i], bfr[j],
                                                            acc[i][j], 0, 0, 0);
    __syncthreads();
  }

  float wv4[4];
#pragma unroll
  for (int j = 0; j < 4; ++j)
    wv4[j] = wvec[(size_t)bz * 4096 + m0 + wn + j * 16 + l15];

  __bf16* Sb = SP + (size_t)bz * 16777216;
  const int wnh = wv >> 1;
#pragma unroll
  for (int i = 0; i < 4; ++i) {
#pragma unroll
    for (int r = 0; r < 4; ++r) {
      const int rl = wm + i * 16 + (kg << 2) + r;
      const float Mh = smq[rl];
      const size_t rowbase = (size_t)(n0 + rl) * 4096 + m0 + wn;
      float se = 0.f;
#pragma unroll
      for (int j = 0; j < 4; ++j) {
        const float p = __expf(acc[i][j][r] + wv4[j] - Mh);
        se += p;
        Sb[rowbase + j * 16 + l15] = (__bf16)p;
      }
#pragma unroll
      for (int off = 1; off < 16; off <<= 1) se += __shfl_xor(se, off);
      if (l15 == 0) smf[wnh * 128 + rl] = se;
    }
  }
  __syncthreads();
  if (t < 128)
    Lpart[(size_t)mblk * 16384 + (size_t)bz * 4096 + n0 + t] =
        smf[t] + smf[128 + t];
}

// ---------------------------------------------------------------------------
// invL[n] = 1 / sum_32 Lpart[j][n]   (transposed layout: both sides coalesced)
// ---------------------------------------------------------------------------
__global__ __launch_bounds__(256) void lsum_kernel(const float* __restrict__ Lp,
                                                   float* __restrict__ invL) {
  const int row = blockIdx.x * 256 + threadIdx.x;
  float L = 0.f;
#pragma unroll
  for (int j = 0; j < 32; ++j) L += Lp[(size_t)j * 16384 + row];
  invL[row] = 1.0f / L;
}

// sred[0] = max hn2, sred[1] = max wvec   (single block, float4)
__global__ __launch_bounds__(256) void reduce_kernel(
    const float* __restrict__ hn2, const float* __restrict__ wvec,
    float* __restrict__ sred) {
  const int t = threadIdx.x;
  const floatx4* h4 = (const floatx4*)hn2;
  const floatx4* w4 = (const floatx4*)wvec;
  float mh = 0.f, mw = -1e30f;
  for (int i = t; i < 4096; i += 256) {
    const floatx4 a = h4[i], b = w4[i];
#pragma unroll
    for (int k = 0; k < 4; ++k) {
      mh = fmaxf(mh, a[k]);
      mw = fmaxf(mw, b[k]);
    }
  }
#pragma unroll
  for (int off = 32; off; off >>= 1) {
    mh = fmaxf(mh, __shfl_down(mh, off));
    mw = fmaxf(mw, __shfl_down(mw, off));
  }
  __shared__ float red[8];
  if ((t & 63) == 0) {
    red[t >> 6] = mh;
    red[4 + (t >> 6)] = mw;
  }
  __syncthreads();
  if (t == 0) {
    sred[0] = fmaxf(fmaxf(red[0], red[1]), fmaxf(red[2], red[3]));
    sred[1] = fmaxf(fmaxf(red[4], red[5]), fmaxf(red[6], red[7]));
  }
}

// ---------------------------------------------------------------------------
// GroupNorm pass 1: partial sums. grid 1024.
// ---------------------------------------------------------------------------
__global__ __launch_bounds__(256) void gn_stats(const float* __restrict__ x,
                                                float* __restrict__ part) {
  const int t = threadIdx.x;
  const size_t base = (size_t)blockIdx.x * 8192;
  const floatx4* xp = (const floatx4*)(x + base);
  float s = 0.f, ss = 0.f;
#pragma unroll
  for (int i = 0; i < 8; ++i) {
    floatx4 v = xp[t + i * 256];
#pragma unroll
    for (int k = 0; k < 4; ++k) {
      s += v[k];
      ss += v[k] * v[k];
    }
  }
#pragma unroll
  for (int off = 32; off; off >>= 1) {
    s += __shfl_down(s, off);
    ss += __shfl_down(ss, off);
  }
  __shared__ float red[8];
  if ((t & 63) == 0) {
    red[t >> 6] = s;
    red[4 + (t >> 6)] = ss;
  }
  __syncthreads();
  if (t == 0) {
    part[blockIdx.x * 2] = red[0] + red[1] + red[2] + red[3];
    part[blockIdx.x * 2 + 1] = red[4] + red[5] + red[6] + red[7];
  }
}

// ---------------------------------------------------------------------------
// GroupNorm pass 2 (finalize fused): x[b][c][n] -> Ht[b][n][c], Hc[b][c][n]
// + fused wvec/hn2 accumulation (round-10 verified, unchanged).
// ---------------------------------------------------------------------------
__global__ __launch_bounds__(256) void gn_xform(
    const float* __restrict__ x, const float* __restrict__ part,
    const float* __restrict__ gamma, const float* __restrict__ beta,
    const float* __restrict__ uq, __bf16* __restrict__ Ht,
    __bf16* __restrict__ Hc, float* __restrict__ wvec,
    float* __restrict__ hn2) {
  __shared__ float tile[64][65];
  __shared__ float lsc[64], lsh[64];
  const int t = threadIdx.x;
  const int b = blockIdx.z;
  const int c0 = blockIdx.y * 64;
  const int n0 = blockIdx.x * 64;

  if (t < 64) {
    const int ch = c0 + t;
    const int bg = b * 32 + (ch >> 4);
    float s = 0.f, ss = 0.f;
#pragma unroll
    for (int k = 0; k < 8; ++k) {
      s += part[(bg * 8 + k) * 2];
      ss += part[(bg * 8 + k) * 2 + 1];
    }
    const float mean = s * (1.f / 65536.f);
    const float var = ss * (1.f / 65536.f) - mean * mean;
    const float rstd = rsqrtf(var + 1e-5f);
    const float g = gamma[ch] * rstd;
    lsc[t] = g;
    lsh[t] = beta[ch] - mean * g;
  }
  __syncthreads();

#pragma unroll
  for (int i = 0; i < 4; ++i) {
    const int slot = i * 256 + t;
    const int c = slot >> 4;
    const int nc = (slot & 15) * 4;
    const int ch = c0 + c;
    const floatx4 v =
        *(const floatx4*)&x[((size_t)b * 512 + ch) * 4096 + n0 + nc];
    const float scl = lsc[c];
    const float shf = lsh[c];
    bf16x4 hv;
#pragma unroll
    for (int k = 0; k < 4; ++k) {
      const float f = v[k] * scl + shf;
      tile[c][nc + k] = f;
      hv[k] = (__bf16)f;
    }
    *(bf16x4*)&Hc[((size_t)b * 512 + ch) * 4096 + n0 + nc] = hv;
  }
  __syncthreads();
#pragma unroll
  for (int i = 0; i < 4; ++i) {
    const int slot = i * 256 + t;
    const int n = slot >> 4;
    const int cc = (slot & 15) * 4;
    const floatx4 uv = *(const floatx4*)&uq[c0 + cc];
    bf16x4 o;
    float ps = 0.f, pn = 0.f;
#pragma unroll
    for (int k = 0; k < 4; ++k) {
      o[k] = (__bf16)tile[cc + k][n];
      const float f = (float)o[k];  // round-tripped: matches old wvec_kernel
      ps += f * uv[k];
      pn += f * f;
    }
    *(bf16x4*)&Ht[((size_t)b * 4096 + n0 + n) * 512 + c0 + cc] = o;
#pragma unroll
    for (int off = 1; off < 16; off <<= 1) {
      ps += __shfl_xor(ps, off);
      pn += __shfl_xor(pn, off);
    }
    if ((t & 15) == 0) {
      const size_t row = (size_t)b * 4096 + n0 + n;
      atomicAdd(&wvec[row], ps);
      atomicAdd(&hn2[row], pn);
    }
  }
}

// ---------------------------------------------------------------------------
// weight prep: z<3 -> transpose+cvt wq/wk/wv; z==3 -> straight cvt wo.
// grid (8,8,4).
// ---------------------------------------------------------------------------
__global__ __launch_bounds__(256) void cvt_kernel(const float* w0,
                                                  const float* w1,
                                                  const float* w2,
                                                  const float* w3, __bf16* o0,
                                                  __bf16* o1, __bf16* o2,
                                                  __bf16* o3) {
  __shared__ float tile[64][65];
  const int t = threadIdx.x;
  const int z = blockIdx.z;
  const int r0 = blockIdx.y * 64;
  const int d0 = blockIdx.x * 64;

  if (z == 3) {
#pragma unroll
    for (int i = 0; i < 4; ++i) {
      const int slot = i * 256 + t;
      const int r = slot >> 4;
      const int cc = (slot & 15) * 4;
      const floatx4 v = *(const floatx4*)&w3[(size_t)(r0 + r) * 512 + d0 + cc];
      bf16x4 ov;
#pragma unroll
      for (int k = 0; k < 4; ++k) ov[k] = (__bf16)v[k];
      *(bf16x4*)&o3[(size_t)(r0 + r) * 512 + d0 + cc] = ov;
    }
    return;
  }
  const float* w = z == 0 ? w0 : z == 1 ? w1 : w2;
  __bf16* o = z == 0 ? o0 : z == 1 ? o1 : o2;
#pragma unroll
  for (int i = 0; i < 4; ++i) {
    const int slot = i * 256 + t;
    const int r = slot >> 4;
    const int cc = (slot & 15) * 4;
    const floatx4 v = *(const floatx4*)&w[(size_t)(r0 + r) * 512 + d0 + cc];
#pragma unroll
    for (int k = 0; k < 4; ++k) tile[r][cc + k] = v[k];
  }
  __syncthreads();
#pragma unroll
  for (int i = 0; i < 4; ++i) {
    const int slot = i * 256 + t;
    const int d = slot >> 4;
    const int cc = (slot & 15) * 4;
    bf16x4 ov;
#pragma unroll
    for (int k = 0; k < 4; ++k) ov[k] = (__bf16)tile[cc + k][d];
    *(bf16x4*)&o[(size_t)(d0 + d) * 512 + r0 + cc] = ov;
  }
}

// ---------------------------------------------------------------------------
// fused bias prep + wvec/hn2 zero-init. grid 1025. (round-10 verified)
// ---------------------------------------------------------------------------
__global__ __launch_bounds__(256) void prep_kernel(
    const float* __restrict__ wk, const float* __restrict__ bq,
    const float* __restrict__ bk, const float* __restrict__ wo,
    const float* __restrict__ bv, const float* __restrict__ bo,
    float* __restrict__ uq, float* __restrict__ bias2, float qscale,
    float* __restrict__ wvec, float* __restrict__ hn2) {
  const int bidx = blockIdx.x;
  const int t = threadIdx.x;
  {
    const int slot = bidx * 256 + t;
    if (slot < 16384)
      wvec[slot] = 0.f;
    else if (slot < 32768)
      hn2[slot - 16384] = 0.f;
  }
  float s = 0.f;
  if (bidx < 512) {
    s = bq[t] * wk[(size_t)t * 512 + bidx] +
        bq[t + 256] * wk[(size_t)(t + 256) * 512 + bidx];
  } else if (bidx < 1024) {
    const int d = bidx - 512;
    s = wo[(size_t)d * 512 + t] * bv[t] +
        wo[(size_t)d * 512 + t + 256] * bv[t + 256];
  } else {
    s = bq[t] * bk[t] + bq[t + 256] * bk[t + 256];
  }
#pragma unroll
  for (int off = 32; off; off >>= 1) s += __shfl_down(s, off);
  __shared__ float red[4];
  if ((t & 63) == 0) red[t >> 6] = s;
  __syncthreads();
  if (t == 0) {
    const float tot = red[0] + red[1] + red[2] + red[3];
    if (bidx < 512)
      uq[bidx] = qscale * tot;
    else if (bidx < 1024)
      bias2[bidx - 512] = tot + bo[bidx - 512];
    else
      uq[512] = qscale * tot;
  }
}

// ---------------------------------------------------------------------------
extern "C" void kernel_launch(void* const* d_in, const int* in_sizes, int n_in,
                              void* d_out, int out_size, void* d_ws,
                              size_t ws_size, hipStream_t stream) {
  const float* x = (const float*)d_in[0];
  const float* gamma = (const float*)d_in[1];
  const float* beta = (const float*)d_in[2];
  const float* wq = (const float*)d_in[3];
  const float* bq = (const float*)d_in[4];
  const float* wk = (const float*)d_in[5];
  const float* bk = (const float*)d_in[6];
  const float* wv = (const float*)d_in[7];
  const float* bv = (const float*)d_in[8];
  const float* wo = (const float*)d_in[9];
  const float* bo = (const float*)d_in[10];

  __bf16* ws = (__bf16*)d_ws;
  __bf16* wqT = ws;                  // 512*512
  __bf16* wkT = wqT + 262144;
  __bf16* wvT = wkT + 262144;
  __bf16* woB = wvT + 262144;
  __bf16* AqkT = woB + 262144;
  __bf16* Wb = AqkT + 262144;
  __bf16* Ht = Wb + 262144;          // [4][4096][512]
  __bf16* Hc = Ht + 8388608;         // [4][512][4096]
  __bf16* G = Hc + 8388608;          // [4][4096][512]
  __bf16* Z = G + 8388608;           // [4][4096][512]
  __bf16* SP = Z + 8388608;          // [4][4096][4096]  P''
  float* Lpart = (float*)(SP + 67108864);  // [32][16384]
  float* invL = Lpart + 524288;            // [16384]
  float* hn2 = invL + 16384;               // [16384]
  float* wvec = hn2 + 16384;               // [16384]
  float* uq = wvec + 16384;                // [513]
  float* bias2 = uq + 1024;                // [512]
  float* sred = bias2 + 512;               // [2]
  float* gn2p = sred + 64;                 // [16384][8]
  const size_t need =
      ((size_t)(6 * 262144 + 4 * 8388608 + 67108864)) * 2 +
      (524288 + 3 * 16384 + 1024 + 512 + 64 + 131072) * 4;
  if (ws_size < need) return;

  // gn scratch in SP region (overwritten later by gemm_qk)
  float* part = (float*)SP;  // [1024][2]

  const float qscale = 0.04419417382415922f;  // 512^-0.5
  const long sH = 2097152;

  cvt_kernel<<<dim3(8, 8, 4), 256, 0, stream>>>(wq, wk, wv, wo, wqT, wkT, wvT,
                                                woB);
  prep_kernel<<<1025, 256, 0, stream>>>(wk, bq, bk, wo, bv, bo, uq, bias2,
                                        qscale, wvec, hn2);
  // AqkT = qscale*wk^T wq ; Wb = wo*wv   (one launch)
  gemm_small<<<dim3(4, 4, 2), 256, 0, stream>>>(wkT, wqT, AqkT, woB, wvT, Wb,
                                                qscale);

  gn_stats<<<1024, 256, 0, stream>>>(x, part);
  // gn finalize + fused wvec/hn2 accumulation
  gn_xform<<<dim3(64, 8, 4), 256, 0, stream>>>(x, part, gamma, beta, uq, Ht,
                                               Hc, wvec, hn2);

  // G[n][j] = Ht[n,:]·AqkT[j,:] + fused ||g_row||^2 partials
  gemm_g<<<dim3(4, 32, 4), 256, 0, stream>>>(Ht, AqkT, G, gn2p);

  reduce_kernel<<<1, 256, 0, stream>>>(hn2, wvec, sred);

  // P'' = exp(s - Mhat) + row-block sums (128^2, BK=64, XCD-swizzled)
  gemm_qk<<<dim3(32, 32, 4), 256, 0, stream>>>(G, Ht, wvec, sred, gn2p, SP,
                                               Lpart);
  lsum_kernel<<<64, 256, 0, stream>>>(Lpart, invL);

  // Z'[n][c] = sum_m P''[n,m]*Hc[c,m]   (BK=64, XCD-swizzled)
  gemm_bt<false><<<dim3(128, 1, 4), 256, 0, stream>>>(
      SP, Hc, Z, nullptr, nullptr, nullptr, 4096, 4096, 512, 16777216, sH, sH,
      0, 4096, 0, 1.0f, 1);

  // y[d][n] = x[d][n] + invL[n]*(Wb·Z')[d][n] + bias2[d]
  gemm_bt<true><<<dim3(32, 4, 4), 256, 0, stream>>>(
      Wb, Z, d_out, bias2, x, invL, 512, 512, 4096, 0, sH, sH, sH, 512, 1,
      1.0f, 0);
}

// Round 13
// 345.838 us; speedup vs baseline: 1.0760x; 1.0760x over previous
//
#include <hip/hip_runtime.h>

typedef __bf16 bf16x8 __attribute__((ext_vector_type(8)));
typedef __bf16 bf16x4 __attribute__((ext_vector_type(4)));
typedef float floatx4 __attribute__((ext_vector_type(4)));

#define AS1(p) ((const __attribute__((address_space(1))) unsigned int*)(p))
#define AS3(p) ((__attribute__((address_space(3))) unsigned int*)(p))

__device__ __forceinline__ void async_cp16(const void* g, void* l) {
  __builtin_amdgcn_global_load_lds(AS1(g), AS3(l), 16, 0, 0);
}

// ---------------------------------------------------------------------------
// BK=64 XOR-swizzled LDS tile [128 rows][64 k] bf16 (chunk = 16B of 8 k,
// 8 chunks/row):  LDS slot s holds G[row = s>>3][chunk (s&7) ^ ((s>>3)&7)].
// Staging linear; source col permuted WITHIN the row's 128B run -> fully
// coalesced. Reads conflict-free (r8/r9 HW-verified family).
// ---------------------------------------------------------------------------

// ---------------------------------------------------------------------------
// Generic bf16 GEMM (round-9 verified form, unchanged):
// C[row][col] = scale * (sum_k A[row,k]*B[col,k] + bias). K % 64 == 0.
// ---------------------------------------------------------------------------
template <bool OUT_F32>
__global__ __launch_bounds__(256, 2) void gemm_bt(
    const __bf16* __restrict__ A, const __bf16* __restrict__ B,
    void* __restrict__ Cv, const float* __restrict__ bias,
    const float* __restrict__ residual, const float* __restrict__ colscale,
    int lda, int ldb, int ldc, long sA, long sB, long sC, long sR, int K,
    int bias_mode, float scale, int swz) {
  __shared__ alignas(16) __bf16 As[128 * 64];
  __shared__ alignas(16) __bf16 Bs[128 * 64];

  const int t = threadIdx.x;
  const int bz = blockIdx.z;
  int bx = blockIdx.x, by = blockIdx.y;
  if (swz) {
    const int xcd = bx & 7, idx = bx >> 3;
    by = xcd + (idx >> 2) * 8;  // row strip 0..31
    bx = idx & 3;               // col block 0..3
  }
  const int m0 = by * 128;
  const int n0 = bx * 128;

  const __bf16* Ab = A + (size_t)bz * sA;
  const __bf16* Bb = B + (size_t)bz * sB;

  const int sr = t >> 3;
  const int sc = ((t & 7) ^ ((t >> 3) & 7)) * 8;
  const __bf16* gA0 = Ab + (size_t)(m0 + sr) * lda + sc;
  const __bf16* gA1 = gA0 + (size_t)32 * lda;
  const __bf16* gA2 = gA0 + (size_t)64 * lda;
  const __bf16* gA3 = gA0 + (size_t)96 * lda;
  const __bf16* gB0 = Bb + (size_t)(n0 + sr) * ldb + sc;
  const __bf16* gB1 = gB0 + (size_t)32 * ldb;
  const __bf16* gB2 = gB0 + (size_t)64 * ldb;
  const __bf16* gB3 = gB0 + (size_t)96 * ldb;
  __bf16* lA0 = &As[t * 8];
  __bf16* lA1 = &As[(t + 256) * 8];
  __bf16* lA2 = &As[(t + 512) * 8];
  __bf16* lA3 = &As[(t + 768) * 8];
  __bf16* lB0 = &Bs[t * 8];
  __bf16* lB1 = &Bs[(t + 256) * 8];
  __bf16* lB2 = &Bs[(t + 512) * 8];
  __bf16* lB3 = &Bs[(t + 768) * 8];

  const int lane = t & 63;
  const int wv = t >> 6;
  const int wm = (wv & 1) * 64;
  const int wn = (wv >> 1) * 64;
  const int l15 = lane & 15;
  const int kg = lane >> 4;
  const int l7 = l15 & 7;

  int aoff0[4], boff0[4], aoff1[4], boff1[4];
#pragma unroll
  for (int i = 0; i < 4; ++i) {
    aoff0[i] = (wm + i * 16 + l15) * 64 + (kg ^ l7) * 8;
    aoff1[i] = (wm + i * 16 + l15) * 64 + ((4 + kg) ^ l7) * 8;
  }
#pragma unroll
  for (int j = 0; j < 4; ++j) {
    boff0[j] = (wn + j * 16 + l15) * 64 + (kg ^ l7) * 8;
    boff1[j] = (wn + j * 16 + l15) * 64 + ((4 + kg) ^ l7) * 8;
  }

  floatx4 acc[4][4] = {};

  const int KT = K >> 6;
  for (int kt = 0; kt < KT; ++kt) {
    const size_t ko = (size_t)kt * 64;
    async_cp16(gA0 + ko, lA0);
    async_cp16(gA1 + ko, lA1);
    async_cp16(gA2 + ko, lA2);
    async_cp16(gA3 + ko, lA3);
    async_cp16(gB0 + ko, lB0);
    async_cp16(gB1 + ko, lB1);
    async_cp16(gB2 + ko, lB2);
    async_cp16(gB3 + ko, lB3);
    __syncthreads();
    bf16x8 af[4], bfr[4];
#pragma unroll
    for (int i = 0; i < 4; ++i) af[i] = *(const bf16x8*)&As[aoff0[i]];
#pragma unroll
    for (int j = 0; j < 4; ++j) bfr[j] = *(const bf16x8*)&Bs[boff0[j]];
#pragma unroll
    for (int i = 0; i < 4; ++i)
#pragma unroll
      for (int j = 0; j < 4; ++j)
        acc[i][j] = __builtin_amdgcn_mfma_f32_16x16x32_bf16(af[i], bfr[j],
                                                            acc[i][j], 0, 0, 0);
#pragma unroll
    for (int i = 0; i < 4; ++i) af[i] = *(const bf16x8*)&As[aoff1[i]];
#pragma unroll
    for (int j = 0; j < 4; ++j) bfr[j] = *(const bf16x8*)&Bs[boff1[j]];
#pragma unroll
    for (int i = 0; i < 4; ++i)
#pragma unroll
      for (int j = 0; j < 4; ++j)
        acc[i][j] = __builtin_amdgcn_mfma_f32_16x16x32_bf16(af[i], bfr[j],
                                                            acc[i][j], 0, 0, 0);
    __syncthreads();
  }

  const int r0 = m0 + wm + (kg << 2);
  const int c0 = n0 + wn + l15;
#pragma unroll
  for (int i = 0; i < 4; ++i) {
#pragma unroll
    for (int r = 0; r < 4; ++r) {
      const int row = r0 + i * 16 + r;
      float brow = 0.f;
      if (bias_mode == 1) brow = bias[row];
#pragma unroll
      for (int j = 0; j < 4; ++j) {
        const int col = c0 + j * 16;
        float v = acc[i][j][r];
        if (OUT_F32 && colscale) v *= colscale[(size_t)bz * 4096 + col];
        if (bias_mode == 1) v += brow;
        v *= scale;
        const size_t off = (size_t)row * ldc + col;
        if (OUT_F32) {
          float* Cf = (float*)Cv + (size_t)bz * sC;
          if (residual) v += residual[(size_t)bz * sR + off];
          Cf[off] = v;
        } else {
          __bf16* Cb = (__bf16*)Cv + (size_t)bz * sC;
          Cb[off] = (__bf16)v;
        }
      }
    }
  }
}

// ---------------------------------------------------------------------------
// G-GEMM with fused ||g_row||^2 partials (round-10 verified, unchanged).
// grid (4 colblk, 32 rowstrip, 4).
// ---------------------------------------------------------------------------
__global__ __launch_bounds__(256, 2) void gemm_g(const __bf16* __restrict__ A,
                                                 const __bf16* __restrict__ B,
                                                 __bf16* __restrict__ C,
                                                 float* __restrict__ gn2p) {
  __shared__ alignas(16) __bf16 As[128 * 64];
  __shared__ alignas(16) __bf16 Bs[128 * 64];

  const int t = threadIdx.x;
  const int bz = blockIdx.z;
  const int m0 = blockIdx.y * 128;  // n rows
  const int n0 = blockIdx.x * 128;  // j cols

  const __bf16* Ab = A + (size_t)bz * 2097152;
  const __bf16* Bb = B;  // shared weights (no batch stride)

  const int sr = t >> 3;
  const int sc = ((t & 7) ^ ((t >> 3) & 7)) * 8;
  const __bf16* gA0 = Ab + (size_t)(m0 + sr) * 512 + sc;
  const __bf16* gA1 = gA0 + (size_t)32 * 512;
  const __bf16* gA2 = gA0 + (size_t)64 * 512;
  const __bf16* gA3 = gA0 + (size_t)96 * 512;
  const __bf16* gB0 = Bb + (size_t)(n0 + sr) * 512 + sc;
  const __bf16* gB1 = gB0 + (size_t)32 * 512;
  const __bf16* gB2 = gB0 + (size_t)64 * 512;
  const __bf16* gB3 = gB0 + (size_t)96 * 512;
  __bf16* lA0 = &As[t * 8];
  __bf16* lA1 = &As[(t + 256) * 8];
  __bf16* lA2 = &As[(t + 512) * 8];
  __bf16* lA3 = &As[(t + 768) * 8];
  __bf16* lB0 = &Bs[t * 8];
  __bf16* lB1 = &Bs[(t + 256) * 8];
  __bf16* lB2 = &Bs[(t + 512) * 8];
  __bf16* lB3 = &Bs[(t + 768) * 8];

  const int lane = t & 63;
  const int wv = t >> 6;
  const int wm = (wv & 1) * 64;
  const int wn = (wv >> 1) * 64;
  const int l15 = lane & 15;
  const int kg = lane >> 4;
  const int l7 = l15 & 7;

  int aoff0[4], boff0[4], aoff1[4], boff1[4];
#pragma unroll
  for (int i = 0; i < 4; ++i) {
    aoff0[i] = (wm + i * 16 + l15) * 64 + (kg ^ l7) * 8;
    aoff1[i] = (wm + i * 16 + l15) * 64 + ((4 + kg) ^ l7) * 8;
  }
#pragma unroll
  for (int j = 0; j < 4; ++j) {
    boff0[j] = (wn + j * 16 + l15) * 64 + (kg ^ l7) * 8;
    boff1[j] = (wn + j * 16 + l15) * 64 + ((4 + kg) ^ l7) * 8;
  }

  floatx4 acc[4][4] = {};

  for (int kt = 0; kt < 8; ++kt) {
    const size_t ko = (size_t)kt * 64;
    async_cp16(gA0 + ko, lA0);
    async_cp16(gA1 + ko, lA1);
    async_cp16(gA2 + ko, lA2);
    async_cp16(gA3 + ko, lA3);
    async_cp16(gB0 + ko, lB0);
    async_cp16(gB1 + ko, lB1);
    async_cp16(gB2 + ko, lB2);
    async_cp16(gB3 + ko, lB3);
    __syncthreads();
    bf16x8 af[4], bfr[4];
#pragma unroll
    for (int i = 0; i < 4; ++i) af[i] = *(const bf16x8*)&As[aoff0[i]];
#pragma unroll
    for (int j = 0; j < 4; ++j) bfr[j] = *(const bf16x8*)&Bs[boff0[j]];
#pragma unroll
    for (int i = 0; i < 4; ++i)
#pragma unroll
      for (int j = 0; j < 4; ++j)
        acc[i][j] = __builtin_amdgcn_mfma_f32_16x16x32_bf16(af[i], bfr[j],
                                                            acc[i][j], 0, 0, 0);
#pragma unroll
    for (int i = 0; i < 4; ++i) af[i] = *(const bf16x8*)&As[aoff1[i]];
#pragma unroll
    for (int j = 0; j < 4; ++j) bfr[j] = *(const bf16x8*)&Bs[boff1[j]];
#pragma unroll
    for (int i = 0; i < 4; ++i)
#pragma unroll
      for (int j = 0; j < 4; ++j)
        acc[i][j] = __builtin_amdgcn_mfma_f32_16x16x32_bf16(af[i], bfr[j],
                                                            acc[i][j], 0, 0, 0);
    __syncthreads();
  }

  __bf16* Cb = C + (size_t)bz * 2097152;
  const int r0 = m0 + wm + (kg << 2);
  const int c0 = n0 + wn + l15;
  const int slot8 = (n0 >> 6) + (wv >> 1);  // colblk*2 + wavehalf, 0..7
#pragma unroll
  for (int i = 0; i < 4; ++i) {
#pragma unroll
    for (int r = 0; r < 4; ++r) {
      const int row = r0 + i * 16 + r;
      float s2 = 0.f;
#pragma unroll
      for (int j = 0; j < 4; ++j) {
        const __bf16 bv = (__bf16)acc[i][j][r];
        Cb[(size_t)row * 512 + c0 + j * 16] = bv;
        const float f = (float)bv;  // round-tripped: matches old gnorm exactly
        s2 += f * f;
      }
#pragma unroll
      for (int off = 1; off < 16; off <<= 1) s2 += __shfl_xor(s2, off);
      if (l15 == 0) gn2p[((size_t)bz * 4096 + row) * 8 + slot8] = s2;
    }
  }
}

// ---------------------------------------------------------------------------
// Two small 512x512x512 GEMMs in one launch. grid (4,4,2).
// (round-8 verified form: BK=32 XOR swizzle; unchanged)
// ---------------------------------------------------------------------------
__global__ __launch_bounds__(256, 2) void gemm_small(
    const __bf16* __restrict__ A0, const __bf16* __restrict__ B0,
    __bf16* __restrict__ C0, const __bf16* __restrict__ A1,
    const __bf16* __restrict__ B1, __bf16* __restrict__ C1, float scale0) {
  __shared__ alignas(16) __bf16 As[128 * 32];
  __shared__ alignas(16) __bf16 Bs[128 * 32];

  const int t = threadIdx.x;
  const int z = blockIdx.z;
  const __bf16* A = z ? A1 : A0;
  const __bf16* B = z ? B1 : B0;
  __bf16* C = z ? C1 : C0;
  const float scale = z ? 1.0f : scale0;
  const int m0 = blockIdx.y * 128;
  const int n0 = blockIdx.x * 128;

  const int sr = t >> 2;
  const int sc = (t & 3) ^ ((t >> 3) & 3);
  const __bf16* gA0 = A + (size_t)(m0 + sr) * 512 + sc * 8;
  const __bf16* gA1 = gA0 + (size_t)64 * 512;
  const __bf16* gB0 = B + (size_t)(n0 + sr) * 512 + sc * 8;
  const __bf16* gB1 = gB0 + (size_t)64 * 512;
  __bf16* lA0 = &As[t * 8];
  __bf16* lA1 = &As[(t + 256) * 8];
  __bf16* lB0 = &Bs[t * 8];
  __bf16* lB1 = &Bs[(t + 256) * 8];

  const int lane = t & 63;
  const int wvv = t >> 6;
  const int wm = (wvv & 1) * 64;
  const int wn = (wvv >> 1) * 64;
  const int l15 = lane & 15;
  const int kg = lane >> 4;

  const int kgs = (kg ^ ((l15 >> 1) & 3)) * 8;
  int aoff[4], boff[4];
#pragma unroll
  for (int i = 0; i < 4; ++i) aoff[i] = (wm + i * 16 + l15) * 32 + kgs;
#pragma unroll
  for (int j = 0; j < 4; ++j) boff[j] = (wn + j * 16 + l15) * 32 + kgs;

  floatx4 acc[4][4] = {};

  for (int kt = 0; kt < 16; ++kt) {
    const size_t ko = (size_t)kt * 32;
    async_cp16(gA0 + ko, lA0);
    async_cp16(gA1 + ko, lA1);
    async_cp16(gB0 + ko, lB0);
    async_cp16(gB1 + ko, lB1);
    __syncthreads();
    bf16x8 af[4], bfr[4];
#pragma unroll
    for (int i = 0; i < 4; ++i) af[i] = *(const bf16x8*)&As[aoff[i]];
#pragma unroll
    for (int j = 0; j < 4; ++j) bfr[j] = *(const bf16x8*)&Bs[boff[j]];
#pragma unroll
    for (int i = 0; i < 4; ++i)
#pragma unroll
      for (int j = 0; j < 4; ++j)
        acc[i][j] = __builtin_amdgcn_mfma_f32_16x16x32_bf16(af[i], bfr[j],
                                                            acc[i][j], 0, 0, 0);
    __syncthreads();
  }

  const int r0 = m0 + wm + (kg << 2);
  const int c0 = n0 + wn + l15;
#pragma unroll
  for (int i = 0; i < 4; ++i)
#pragma unroll
    for (int r = 0; r < 4; ++r) {
      const int row = r0 + i * 16 + r;
#pragma unroll
      for (int j = 0; j < 4; ++j)
        C[(size_t)row * 512 + c0 + j * 16] = (__bf16)(acc[i][j][r] * scale);
    }
}

// ---------------------------------------------------------------------------
// QK^T GEMM + P'' = exp(s - Mhat). 128x128 tile, BK=64 XOR-swizzled
// (round-9/10 verified: ~87 us, 0 conflicts). Block mapping reverted to the
// PLAIN grid form (r12 lesson: id=by*32+bx with HW xcd=id%8 already gives
// each XCD a permanent 4-m-block Ht partition -> 512KB L2-resident; the
// "smart" remap thrashed L2, FETCH 74->125MB). Lpart stays transposed
// [mblk][16384] (coalesced write, r12's one win: WRITE 147->133MB).
// grid (32 mblk, 32 nblk, 4).
// ---------------------------------------------------------------------------
__global__ __launch_bounds__(256, 2) void gemm_qk(
    const __bf16* __restrict__ G, const __bf16* __restrict__ Ht,
    const float* __restrict__ wvec, const float* __restrict__ sred,
    const float* __restrict__ gn2p, __bf16* __restrict__ SP,
    float* __restrict__ Lpart) {
  __shared__ alignas(16) __bf16 As[128 * 64];
  __shared__ alignas(16) __bf16 Bs[128 * 64];
  __shared__ float smq[128];
  __shared__ float smf[256];

  const int t = threadIdx.x;
  const int bz = blockIdx.z;
  const int mblk = blockIdx.x;
  const int m0 = mblk * 128;        // key cols
  const int n0 = blockIdx.y * 128;  // query rows
  const long sH = 2097152;

  const __bf16* Ab = G + (size_t)bz * sH;
  const __bf16* Bb = Ht + (size_t)bz * sH;

  const int sr = t >> 3;
  const int sc = ((t & 7) ^ ((t >> 3) & 7)) * 8;
  const __bf16* gA0 = Ab + (size_t)(n0 + sr) * 512 + sc;
  const __bf16* gA1 = gA0 + (size_t)32 * 512;
  const __bf16* gA2 = gA0 + (size_t)64 * 512;
  const __bf16* gA3 = gA0 + (size_t)96 * 512;
  const __bf16* gB0 = Bb + (size_t)(m0 + sr) * 512 + sc;
  const __bf16* gB1 = gB0 + (size_t)32 * 512;
  const __bf16* gB2 = gB0 + (size_t)64 * 512;
  const __bf16* gB3 = gB0 + (size_t)96 * 512;
  __bf16* lA0 = &As[t * 8];
  __bf16* lA1 = &As[(t + 256) * 8];
  __bf16* lA2 = &As[(t + 512) * 8];
  __bf16* lA3 = &As[(t + 768) * 8];
  __bf16* lB0 = &Bs[t * 8];
  __bf16* lB1 = &Bs[(t + 256) * 8];
  __bf16* lB2 = &Bs[(t + 512) * 8];
  __bf16* lB3 = &Bs[(t + 768) * 8];

  const int lane = t & 63;
  const int wv = t >> 6;
  const int wm = (wv & 1) * 64;  // query-row half
  const int wn = (wv >> 1) * 64; // key-col half
  const int l15 = lane & 15;
  const int kg = lane >> 4;
  const int l7 = l15 & 7;

  // Mhat per local query row (hidden under first staging)
  if (t < 128) {
    const floatx4* gp =
        (const floatx4*)&gn2p[((size_t)bz * 4096 + n0 + t) * 8];
    const floatx4 a = gp[0], b = gp[1];
    const float g2 = a[0] + a[1] + a[2] + a[3] + b[0] + b[1] + b[2] + b[3];
    smq[t] = sqrtf(g2) * sqrtf(sred[0]) + sred[1];
  }

  int aoff0[4], boff0[4], aoff1[4], boff1[4];
#pragma unroll
  for (int i = 0; i < 4; ++i) {
    aoff0[i] = (wm + i * 16 + l15) * 64 + (kg ^ l7) * 8;
    aoff1[i] = (wm + i * 16 + l15) * 64 + ((4 + kg) ^ l7) * 8;
  }
#pragma unroll
  for (int j = 0; j < 4; ++j) {
    boff0[j] = (wn + j * 16 + l15) * 64 + (kg ^ l7) * 8;
    boff1[j] = (wn + j * 16 + l15) * 64 + ((4 + kg) ^ l7) * 8;
  }

  floatx4 acc[4][4] = {};

  for (int kt = 0; kt < 8; ++kt) {
    const size_t ko = (size_t)kt * 64;
    async_cp16(gA0 + ko, lA0);
    async_cp16(gA1 + ko, lA1);
    async_cp16(gA2 + ko, lA2);
    async_cp16(gA3 + ko, lA3);
    async_cp16(gB0 + ko, lB0);
    async_cp16(gB1 + ko, lB1);
    async_cp16(gB2 + ko, lB2);
    async_cp16(gB3 + ko, lB3);
    __syncthreads();
    bf16x8 af[4], bfr[4];
#pragma unroll
    for (int i = 0; i < 4; ++i) af[i] = *(const bf16x8*)&As[aoff0[i]];
#pragma unroll
    for (int j = 0; j < 4; ++j) bfr[j] = *(const bf16x8*)&Bs[boff0[j]];
#pragma unroll
    for (int i = 0; i < 4; ++i)
#pragma unroll
      for (int j = 0; j < 4; ++j)
        acc[i][j] = __builtin_amdgcn_mfma_f32_16x16x32_bf16(af[i], bfr[j],
                                                            acc[i][j], 0, 0, 0);
#pragma unroll
    for (int i = 0; i < 4; ++i) af[i] = *(const bf16x8*)&As[aoff1[i]];
#pragma unroll
    for (int j = 0; j < 4; ++j) bfr[j] = *(const bf16x8*)&Bs[boff1[j]];
#pragma unroll
    for (int i = 0; i < 4; ++i)
#pragma unroll
      for (int j = 0; j < 4; ++j)
        acc[i][j] = __builtin_amdgcn_mfma_f32_16x16x32_bf16(af[i], bfr[j],
                                                            acc[i][j], 0, 0, 0);
    __syncthreads();
  }

  float wv4[4];
#pragma unroll
  for (int j = 0; j < 4; ++j)
    wv4[j] = wvec[(size_t)bz * 4096 + m0 + wn + j * 16 + l15];

  __bf16* Sb = SP + (size_t)bz * 16777216;
  const int wnh = wv >> 1;
#pragma unroll
  for (int i = 0; i < 4; ++i) {
#pragma unroll
    for (int r = 0; r < 4; ++r) {
      const int rl = wm + i * 16 + (kg << 2) + r;
      const float Mh = smq[rl];
      const size_t rowbase = (size_t)(n0 + rl) * 4096 + m0 + wn;
      float se = 0.f;
#pragma unroll
      for (int j = 0; j < 4; ++j) {
        const float p = __expf(acc[i][j][r] + wv4[j] - Mh);
        se += p;
        Sb[rowbase + j * 16 + l15] = (__bf16)p;
      }
#pragma unroll
      for (int off = 1; off < 16; off <<= 1) se += __shfl_xor(se, off);
      if (l15 == 0) smf[wnh * 128 + rl] = se;
    }
  }
  __syncthreads();
  if (t < 128)
    Lpart[(size_t)mblk * 16384 + (size_t)bz * 4096 + n0 + t] =
        smf[t] + smf[128 + t];
}

// ---------------------------------------------------------------------------
// invL[n] = 1 / sum_32 Lpart[j][n]   (transposed layout: both sides coalesced)
// ---------------------------------------------------------------------------
__global__ __launch_bounds__(256) void lsum_kernel(const float* __restrict__ Lp,
                                                   float* __restrict__ invL) {
  const int row = blockIdx.x * 256 + threadIdx.x;
  float L = 0.f;
#pragma unroll
  for (int j = 0; j < 32; ++j) L += Lp[(size_t)j * 16384 + row];
  invL[row] = 1.0f / L;
}

// sred[0] = max hn2, sred[1] = max wvec   (single block, float4)
__global__ __launch_bounds__(256) void reduce_kernel(
    const float* __restrict__ hn2, const float* __restrict__ wvec,
    float* __restrict__ sred) {
  const int t = threadIdx.x;
  const floatx4* h4 = (const floatx4*)hn2;
  const floatx4* w4 = (const floatx4*)wvec;
  float mh = 0.f, mw = -1e30f;
  for (int i = t; i < 4096; i += 256) {
    const floatx4 a = h4[i], b = w4[i];
#pragma unroll
    for (int k = 0; k < 4; ++k) {
      mh = fmaxf(mh, a[k]);
      mw = fmaxf(mw, b[k]);
    }
  }
#pragma unroll
  for (int off = 32; off; off >>= 1) {
    mh = fmaxf(mh, __shfl_down(mh, off));
    mw = fmaxf(mw, __shfl_down(mw, off));
  }
  __shared__ float red[8];
  if ((t & 63) == 0) {
    red[t >> 6] = mh;
    red[4 + (t >> 6)] = mw;
  }
  __syncthreads();
  if (t == 0) {
    sred[0] = fmaxf(fmaxf(red[0], red[1]), fmaxf(red[2], red[3]));
    sred[1] = fmaxf(fmaxf(red[4], red[5]), fmaxf(red[6], red[7]));
  }
}

// ---------------------------------------------------------------------------
// GroupNorm pass 1: partial sums. grid 1024.
// ---------------------------------------------------------------------------
__global__ __launch_bounds__(256) void gn_stats(const float* __restrict__ x,
                                                float* __restrict__ part) {
  const int t = threadIdx.x;
  const size_t base = (size_t)blockIdx.x * 8192;
  const floatx4* xp = (const floatx4*)(x + base);
  float s = 0.f, ss = 0.f;
#pragma unroll
  for (int i = 0; i < 8; ++i) {
    floatx4 v = xp[t + i * 256];
#pragma unroll
    for (int k = 0; k < 4; ++k) {
      s += v[k];
      ss += v[k] * v[k];
    }
  }
#pragma unroll
  for (int off = 32; off; off >>= 1) {
    s += __shfl_down(s, off);
    ss += __shfl_down(ss, off);
  }
  __shared__ float red[8];
  if ((t & 63) == 0) {
    red[t >> 6] = s;
    red[4 + (t >> 6)] = ss;
  }
  __syncthreads();
  if (t == 0) {
    part[blockIdx.x * 2] = red[0] + red[1] + red[2] + red[3];
    part[blockIdx.x * 2 + 1] = red[4] + red[5] + red[6] + red[7];
  }
}

// ---------------------------------------------------------------------------
// GroupNorm pass 2 (finalize fused): x[b][c][n] -> Ht[b][n][c], Hc[b][c][n]
// + fused wvec/hn2 accumulation (round-10 verified, unchanged).
// ---------------------------------------------------------------------------
__global__ __launch_bounds__(256) void gn_xform(
    const float* __restrict__ x, const float* __restrict__ part,
    const float* __restrict__ gamma, const float* __restrict__ beta,
    const float* __restrict__ uq, __bf16* __restrict__ Ht,
    __bf16* __restrict__ Hc, float* __restrict__ wvec,
    float* __restrict__ hn2) {
  __shared__ float tile[64][65];
  __shared__ float lsc[64], lsh[64];
  const int t = threadIdx.x;
  const int b = blockIdx.z;
  const int c0 = blockIdx.y * 64;
  const int n0 = blockIdx.x * 64;

  if (t < 64) {
    const int ch = c0 + t;
    const int bg = b * 32 + (ch >> 4);
    float s = 0.f, ss = 0.f;
#pragma unroll
    for (int k = 0; k < 8; ++k) {
      s += part[(bg * 8 + k) * 2];
      ss += part[(bg * 8 + k) * 2 + 1];
    }
    const float mean = s * (1.f / 65536.f);
    const float var = ss * (1.f / 65536.f) - mean * mean;
    const float rstd = rsqrtf(var + 1e-5f);
    const float g = gamma[ch] * rstd;
    lsc[t] = g;
    lsh[t] = beta[ch] - mean * g;
  }
  __syncthreads();

#pragma unroll
  for (int i = 0; i < 4; ++i) {
    const int slot = i * 256 + t;
    const int c = slot >> 4;
    const int nc = (slot & 15) * 4;
    const int ch = c0 + c;
    const floatx4 v =
        *(const floatx4*)&x[((size_t)b * 512 + ch) * 4096 + n0 + nc];
    const float scl = lsc[c];
    const float shf = lsh[c];
    bf16x4 hv;
#pragma unroll
    for (int k = 0; k < 4; ++k) {
      const float f = v[k] * scl + shf;
      tile[c][nc + k] = f;
      hv[k] = (__bf16)f;
    }
    *(bf16x4*)&Hc[((size_t)b * 512 + ch) * 4096 + n0 + nc] = hv;
  }
  __syncthreads();
#pragma unroll
  for (int i = 0; i < 4; ++i) {
    const int slot = i * 256 + t;
    const int n = slot >> 4;
    const int cc = (slot & 15) * 4;
    const floatx4 uv = *(const floatx4*)&uq[c0 + cc];
    bf16x4 o;
    float ps = 0.f, pn = 0.f;
#pragma unroll
    for (int k = 0; k < 4; ++k) {
      o[k] = (__bf16)tile[cc + k][n];
      const float f = (float)o[k];  // round-tripped: matches old wvec_kernel
      ps += f * uv[k];
      pn += f * f;
    }
    *(bf16x4*)&Ht[((size_t)b * 4096 + n0 + n) * 512 + c0 + cc] = o;
#pragma unroll
    for (int off = 1; off < 16; off <<= 1) {
      ps += __shfl_xor(ps, off);
      pn += __shfl_xor(pn, off);
    }
    if ((t & 15) == 0) {
      const size_t row = (size_t)b * 4096 + n0 + n;
      atomicAdd(&wvec[row], ps);
      atomicAdd(&hn2[row], pn);
    }
  }
}

// ---------------------------------------------------------------------------
// weight prep: z<3 -> transpose+cvt wq/wk/wv; z==3 -> straight cvt wo.
// grid (8,8,4).
// ---------------------------------------------------------------------------
__global__ __launch_bounds__(256) void cvt_kernel(const float* w0,
                                                  const float* w1,
                                                  const float* w2,
                                                  const float* w3, __bf16* o0,
                                                  __bf16* o1, __bf16* o2,
                                                  __bf16* o3) {
  __shared__ float tile[64][65];
  const int t = threadIdx.x;
  const int z = blockIdx.z;
  const int r0 = blockIdx.y * 64;
  const int d0 = blockIdx.x * 64;

  if (z == 3) {
#pragma unroll
    for (int i = 0; i < 4; ++i) {
      const int slot = i * 256 + t;
      const int r = slot >> 4;
      const int cc = (slot & 15) * 4;
      const floatx4 v = *(const floatx4*)&w3[(size_t)(r0 + r) * 512 + d0 + cc];
      bf16x4 ov;
#pragma unroll
      for (int k = 0; k < 4; ++k) ov[k] = (__bf16)v[k];
      *(bf16x4*)&o3[(size_t)(r0 + r) * 512 + d0 + cc] = ov;
    }
    return;
  }
  const float* w = z == 0 ? w0 : z == 1 ? w1 : w2;
  __bf16* o = z == 0 ? o0 : z == 1 ? o1 : o2;
#pragma unroll
  for (int i = 0; i < 4; ++i) {
    const int slot = i * 256 + t;
    const int r = slot >> 4;
    const int cc = (slot & 15) * 4;
    const floatx4 v = *(const floatx4*)&w[(size_t)(r0 + r) * 512 + d0 + cc];
#pragma unroll
    for (int k = 0; k < 4; ++k) tile[r][cc + k] = v[k];
  }
  __syncthreads();
#pragma unroll
  for (int i = 0; i < 4; ++i) {
    const int slot = i * 256 + t;
    const int d = slot >> 4;
    const int cc = (slot & 15) * 4;
    bf16x4 ov;
#pragma unroll
    for (int k = 0; k < 4; ++k) ov[k] = (__bf16)tile[cc + k][d];
    *(bf16x4*)&o[(size_t)(d0 + d) * 512 + r0 + cc] = ov;
  }
}

// ---------------------------------------------------------------------------
// fused bias prep + wvec/hn2 zero-init. grid 1025. (round-10 verified)
// ---------------------------------------------------------------------------
__global__ __launch_bounds__(256) void prep_kernel(
    const float* __restrict__ wk, const float* __restrict__ bq,
    const float* __restrict__ bk, const float* __restrict__ wo,
    const float* __restrict__ bv, const float* __restrict__ bo,
    float* __restrict__ uq, float* __restrict__ bias2, float qscale,
    float* __restrict__ wvec, float* __restrict__ hn2) {
  const int bidx = blockIdx.x;
  const int t = threadIdx.x;
  {
    const int slot = bidx * 256 + t;
    if (slot < 16384)
      wvec[slot] = 0.f;
    else if (slot < 32768)
      hn2[slot - 16384] = 0.f;
  }
  float s = 0.f;
  if (bidx < 512) {
    s = bq[t] * wk[(size_t)t * 512 + bidx] +
        bq[t + 256] * wk[(size_t)(t + 256) * 512 + bidx];
  } else if (bidx < 1024) {
    const int d = bidx - 512;
    s = wo[(size_t)d * 512 + t] * bv[t] +
        wo[(size_t)d * 512 + t + 256] * bv[t + 256];
  } else {
    s = bq[t] * bk[t] + bq[t + 256] * bk[t + 256];
  }
#pragma unroll
  for (int off = 32; off; off >>= 1) s += __shfl_down(s, off);
  __shared__ float red[4];
  if ((t & 63) == 0) red[t >> 6] = s;
  __syncthreads();
  if (t == 0) {
    const float tot = red[0] + red[1] + red[2] + red[3];
    if (bidx < 512)
      uq[bidx] = qscale * tot;
    else if (bidx < 1024)
      bias2[bidx - 512] = tot + bo[bidx - 512];
    else
      uq[512] = qscale * tot;
  }
}

// ---------------------------------------------------------------------------
extern "C" void kernel_launch(void* const* d_in, const int* in_sizes, int n_in,
                              void* d_out, int out_size, void* d_ws,
                              size_t ws_size, hipStream_t stream) {
  const float* x = (const float*)d_in[0];
  const float* gamma = (const float*)d_in[1];
  const float* beta = (const float*)d_in[2];
  const float* wq = (const float*)d_in[3];
  const float* bq = (const float*)d_in[4];
  const float* wk = (const float*)d_in[5];
  const float* bk = (const float*)d_in[6];
  const float* wv = (const float*)d_in[7];
  const float* bv = (const float*)d_in[8];
  const float* wo = (const float*)d_in[9];
  const float* bo = (const float*)d_in[10];

  __bf16* ws = (__bf16*)d_ws;
  __bf16* wqT = ws;                  // 512*512
  __bf16* wkT = wqT + 262144;
  __bf16* wvT = wkT + 262144;
  __bf16* woB = wvT + 262144;
  __bf16* AqkT = woB + 262144;
  __bf16* Wb = AqkT + 262144;
  __bf16* Ht = Wb + 262144;          // [4][4096][512]
  __bf16* Hc = Ht + 8388608;         // [4][512][4096]
  __bf16* G = Hc + 8388608;          // [4][4096][512]
  __bf16* Z = G + 8388608;           // [4][4096][512]
  __bf16* SP = Z + 8388608;          // [4][4096][4096]  P''
  float* Lpart = (float*)(SP + 67108864);  // [32][16384]
  float* invL = Lpart + 524288;            // [16384]
  float* hn2 = invL + 16384;               // [16384]
  float* wvec = hn2 + 16384;               // [16384]
  float* uq = wvec + 16384;                // [513]
  float* bias2 = uq + 1024;                // [512]
  float* sred = bias2 + 512;               // [2]
  float* gn2p = sred + 64;                 // [16384][8]
  const size_t need =
      ((size_t)(6 * 262144 + 4 * 8388608 + 67108864)) * 2 +
      (524288 + 3 * 16384 + 1024 + 512 + 64 + 131072) * 4;
  if (ws_size < need) return;

  // gn scratch in SP region (overwritten later by gemm_qk)
  float* part = (float*)SP;  // [1024][2]

  const float qscale = 0.04419417382415922f;  // 512^-0.5
  const long sH = 2097152;

  cvt_kernel<<<dim3(8, 8, 4), 256, 0, stream>>>(wq, wk, wv, wo, wqT, wkT, wvT,
                                                woB);
  prep_kernel<<<1025, 256, 0, stream>>>(wk, bq, bk, wo, bv, bo, uq, bias2,
                                        qscale, wvec, hn2);
  // AqkT = qscale*wk^T wq ; Wb = wo*wv   (one launch)
  gemm_small<<<dim3(4, 4, 2), 256, 0, stream>>>(wkT, wqT, AqkT, woB, wvT, Wb,
                                                qscale);

  gn_stats<<<1024, 256, 0, stream>>>(x, part);
  // gn finalize + fused wvec/hn2 accumulation
  gn_xform<<<dim3(64, 8, 4), 256, 0, stream>>>(x, part, gamma, beta, uq, Ht,
                                               Hc, wvec, hn2);

  // G[n][j] = Ht[n,:]·AqkT[j,:] + fused ||g_row||^2 partials
  gemm_g<<<dim3(4, 32, 4), 256, 0, stream>>>(Ht, AqkT, G, gn2p);

  reduce_kernel<<<1, 256, 0, stream>>>(hn2, wvec, sred);

  // P'' = exp(s - Mhat) + row-block sums (128^2, BK=64, plain grid)
  gemm_qk<<<dim3(32, 32, 4), 256, 0, stream>>>(G, Ht, wvec, sred, gn2p, SP,
                                               Lpart);
  lsum_kernel<<<64, 256, 0, stream>>>(Lpart, invL);

  // Z'[n][c] = sum_m P''[n,m]*Hc[c,m]   (BK=64, XCD-swizzled)
  gemm_bt<false><<<dim3(128, 1, 4), 256, 0, stream>>>(
      SP, Hc, Z, nullptr, nullptr, nullptr, 4096, 4096, 512, 16777216, sH, sH,
      0, 4096, 0, 1.0f, 1);

  // y[d][n] = x[d][n] + invL[n]*(Wb·Z')[d][n] + bias2[d]
  gemm_bt<true><<<dim3(32, 4, 4), 256, 0, stream>>>(
      Wb, Z, d_out, bias2, x, invL, 512, 512, 4096, 0, sH, sH, sH, 512, 1,
      1.0f, 0);
}